// Round 14
// baseline (203.540 us; speedup 1.0000x reference)
//
#include <hip/hip_runtime.h>
#include <hip/hip_bf16.h>

typedef __attribute__((ext_vector_type(8))) short bf16x8_t;
typedef __attribute__((ext_vector_type(4))) float f32x4_t;
typedef __attribute__((ext_vector_type(8))) unsigned short u16x8_t;

__device__ inline unsigned short bfr(float f) {
    __hip_bfloat16 h = __float2bfloat16(f);   // RNE
    return *reinterpret_cast<unsigned short*>(&h);
}

__device__ inline u16x8_t cvt8(float4 x, float4 y) {
    u16x8_t v;
    v[0] = bfr(x.x); v[1] = bfr(x.y); v[2] = bfr(x.z); v[3] = bfr(x.w);
    v[4] = bfr(y.x); v[5] = bfr(y.y); v[6] = bfr(y.z); v[7] = bfr(y.w);
    return v;
}

// ---- 256x256-tile GEMM+LSE, 16 waves (64x64 each), fused f32->bf16 --------
// R14: halve logical L2 panel traffic vs 128^2 (3.3 GB -> 1.8 GB) while
// keeping 16 waves/CU: 1024 threads, acc=64 VGPR/wave -> 4 waves/SIMD.
// BK=32, 2-slot LDS (2 x 32KB), ONE barrier per K-step: compute slot[t&1]
// while staging slot[(t+1)&1] (disjoint); barrier covers both deps.
// blocks (XCD-swizzled over 1224 = 8*153): lb 0..647 overlap (8 batches x
// 9x9 tiles, supertiled 3 sc x (9 brow x 3 bcol) => B-panels L2-resident),
// lb 648..1223 tile (64 batches x 3x3, rows>=576 duplicated & masked).
// Swizzle (R8-verified 0-conflict): 16B-chunk phys = logical ^ ((row>>1)&3)
// on global source + ds_read; LDS linear; wave writes are 1KB-contiguous.
// ws float layout:
// [0) rs_ov 18432 | [18432) cs_ov 18432 | [36864) dg_ov 18432
// [55296) rs_t 36864 | [92160) cs_t 36864 | [129024) dg_t 36864 -> 165888
__global__ __launch_bounds__(1024, 1) void gemm256_lse_all(
    const float* __restrict__ z1, const float* __restrict__ z2,
    float* __restrict__ ws) {
    const int tid  = threadIdx.x;
    const int lane = tid & 63;
    const int w    = tid >> 6;        // 0..15
    const int wr   = w >> 2;          // 0..3 (rows: wr*64)
    const int wc   = w & 3;           // 0..3 (cols: wc*64)
    const int lr   = lane & 15;
    const int lg   = lane >> 4;       // 0..3

    // T1: XCD-aware bijective swizzle over 1224 = 8*153 blocks
    const int bid = blockIdx.x;
    const int lb  = (bid & 7) * 153 + (bid >> 3);

    int M, batch, brow, bcol;
    float inv_tau;
    float *rs, *cs, *dg;
    bool ov = (lb < 648);
    if (ov) {
        M = 2304; inv_tau = 1.0f / 0.07f;
        rs = ws; cs = ws + 18432; dg = ws + 36864;
        batch = lb / 81;
        int rem = lb - batch * 81;
        int sc = rem / 27, r2 = rem - sc * 27;
        brow = r2 / 3;
        bcol = sc * 3 + (r2 - brow * 3);
    } else {
        M = 576; inv_tau = 1.0f / 0.2f;
        rs = ws + 55296; cs = ws + 92160; dg = ws + 129024;
        int tl = lb - 648;
        batch = tl / 9;
        int rem = tl - batch * 9;
        brow = rem / 3;
        bcol = rem - brow * 3;
    }

    // 2 slots x (A[256][32] + B[256][32]) bf16 = 2 x 16384 ushorts = 64 KiB
    __shared__ unsigned short smem[32768];
    __shared__ int offA[256], offB[256];

    if (tid < 256) {
        int r = brow * 256 + tid;
        int off;
        if (ov) {
            int b = r / 288, rm = r % 288, h = rm / 12, j = rm % 12;
            off = ((b * 8 + batch) * 576 + h * 24 + 12 + j) * 768;
        } else {
            off = ((r < M) ? (batch * 576 + r) : (batch * 576)) * 768;
        }
        offA[tid] = off;
    } else if (tid < 512) {
        int c = bcol * 256 + (tid - 256);
        int off;
        if (ov) {
            int b = c / 288, rm = c % 288, h = rm / 12, j = rm % 12;
            off = ((b * 8 + ((batch + 1) & 7)) * 576 + h * 24 + j) * 768;
        } else {
            off = ((c < M) ? (batch * 576 + c) : (batch * 576)) * 768;
        }
        offB[tid - 256] = off;
    }
    __syncthreads();

    // staging: thread covers row tid>>2 (0..255), phys 16B-chunk tid&3;
    // source fetches logical chunk (tid&3)^((row>>1)&3) = 8 floats (2xfloat4).
    const int srow = tid >> 2;
    const int sc4  = ((tid & 3) ^ ((srow >> 1) & 3)) << 3;  // element offset
    const int srcA = offA[srow] + sc4;
    const int srcB = offB[srow] + sc4;
    const int dstA = srow * 32 + (tid & 3) * 8;              // linear (ushorts)
    const int dstB = 8192 + dstA;

    // swizzled read offsets (ushort units within a slot)
    int aoff[4], boff[4];
#pragma unroll
    for (int i = 0; i < 4; ++i) {
        int ra = wr * 64 + i * 16 + lr;
        aoff[i] = ra * 32 + ((lg ^ ((ra >> 1) & 3)) << 3);
        int rb = wc * 64 + i * 16 + lr;
        boff[i] = 8192 + rb * 32 + ((lg ^ ((rb >> 1) & 3)) << 3);
    }

    f32x4_t acc[4][4];
#pragma unroll
    for (int i = 0; i < 4; ++i)
#pragma unroll
        for (int j = 0; j < 4; ++j) acc[i][j] = (f32x4_t){0.f, 0.f, 0.f, 0.f};

#define STG(T) do { \
    const int sl_ = ((T) & 1) << 14; const int k0_ = (T) * 32; \
    float4 fa0 = *(const float4*)(z1 + srcA + k0_); \
    float4 fa1 = *(const float4*)(z1 + srcA + k0_ + 4); \
    float4 fb0 = *(const float4*)(z2 + srcB + k0_); \
    float4 fb1 = *(const float4*)(z2 + srcB + k0_ + 4); \
    *(u16x8_t*)&smem[sl_ + dstA] = cvt8(fa0, fa1); \
    *(u16x8_t*)&smem[sl_ + dstB] = cvt8(fb0, fb1); \
} while (0)

    STG(0);
    __syncthreads();

    for (int t = 0; t < 24; ++t) {
        const unsigned short* S = &smem[(t & 1) << 14];
        if (t < 23) STG(t + 1);                 // disjoint slot: no barrier
        bf16x8_t av[4], bv[4];
#pragma unroll
        for (int i = 0; i < 4; ++i) av[i] = *(const bf16x8_t*)&S[aoff[i]];
#pragma unroll
        for (int j = 0; j < 4; ++j) bv[j] = *(const bf16x8_t*)&S[boff[j]];
        __builtin_amdgcn_s_setprio(1);
#pragma unroll
        for (int i = 0; i < 4; ++i)
#pragma unroll
            for (int j = 0; j < 4; ++j)
                acc[i][j] = __builtin_amdgcn_mfma_f32_16x16x32_bf16(
                    av[i], bv[j], acc[i][j], 0, 0, 0);
        __builtin_amdgcn_s_setprio(0);
        __syncthreads();   // readers of slot t done + writes of t+1 visible
    }
#undef STG

    // Epilogue: L = acc*inv_tau; exp row/col partial sums; diag.
    const int rowbase = brow * 256 + wr * 64;
    const int colbase = bcol * 256 + wc * 64;
    float colacc[4] = {0.f, 0.f, 0.f, 0.f};
#pragma unroll
    for (int i = 0; i < 4; ++i) {
#pragma unroll
        for (int reg = 0; reg < 4; ++reg) {
            int row = rowbase + i * 16 + lg * 4 + reg;
            bool rv = row < M;
            float rp = 0.f;
#pragma unroll
            for (int j = 0; j < 4; ++j) {
                int col = colbase + j * 16 + lr;
                float L = acc[i][j][reg] * inv_tau;
                float e = (rv && (col < M)) ? __expf(L) : 0.f;
                rp += e;
                colacc[j] += e;
                if (rv && row == col) dg[batch * M + row] = L;
            }
#pragma unroll
            for (int s = 1; s < 16; s <<= 1) rp += __shfl_xor(rp, s);
            if (lr == 0 && rv) atomicAdd(&rs[batch * M + row], rp);
        }
    }
#pragma unroll
    for (int j = 0; j < 4; ++j) {
        float cv = colacc[j];
        cv += __shfl_xor(cv, 16);
        cv += __shfl_xor(cv, 32);
        int col = colbase + j * 16 + lr;
        if (lg == 0 && col < M) atomicAdd(&cs[batch * M + col], cv);
    }
}

// parallel finalize; out[0] pre-zeroed, one atomicAdd per block.
__global__ __launch_bounds__(256) void finalize_kernel(
    const float* __restrict__ ws, float* __restrict__ out) {
    const float* rs_ov = ws;
    const float* cs_ov = ws + 18432;
    const float* dg_ov = ws + 36864;
    const float* rs_t  = ws + 55296;
    const float* cs_t  = ws + 92160;
    const float* dg_t  = ws + 129024;
    const int g0 = blockIdx.x * blockDim.x + threadIdx.x;
    const int gs = gridDim.x * blockDim.x;
    float s_ov = 0.f, s_t = 0.f;
    for (int i = g0; i < 18432; i += gs)
        s_ov += logf(rs_ov[i]) + logf(cs_ov[i]) - 2.f * dg_ov[i];
    for (int i = g0; i < 36864; i += gs)
        s_t += logf(rs_t[i]) + logf(cs_t[i]) - 2.f * dg_t[i];
    float c = 0.5f * s_ov / 18432.f + 0.05f * s_t / 36864.f;
#pragma unroll
    for (int s = 1; s < 64; s <<= 1) c += __shfl_xor(c, s);
    __shared__ float red[4];
    int wv = threadIdx.x >> 6;
    if ((threadIdx.x & 63) == 0) red[wv] = c;
    __syncthreads();
    if (threadIdx.x == 0)
        atomicAdd(out, red[0] + red[1] + red[2] + red[3]);
}

extern "C" void kernel_launch(void* const* d_in, const int* in_sizes, int n_in,
                              void* d_out, int out_size, void* d_ws, size_t ws_size,
                              hipStream_t stream) {
    const float* z1 = (const float*)d_in[0];
    const float* z2 = (const float*)d_in[1];
    float* out = (float*)d_out;
    float* ws  = (float*)d_ws;

    const size_t ACC_B = 165888 * sizeof(float);
    hipMemsetAsync(d_ws, 0, ACC_B, stream);
    hipMemsetAsync(d_out, 0, sizeof(float), stream);

    gemm256_lse_all<<<1224, 1024, 0, stream>>>(z1, z2, ws);
    finalize_kernel<<<16, 256, 0, stream>>>(ws, out);
}